// Round 17
// baseline (2087.041 us; speedup 1.0000x reference)
//
#include <hip/hip_runtime.h>
#include <hip/hip_bf16.h>
#include <stdint.h>

#define KDIM 1024
#define NROW 4096
#define NCOL 4096
#define INFV 1e30f
#define INFBITS 0x7149F2CAu     // bits of 1e30f
#define BM 128
#define BK 32

#define SKROWS 4160             // skewed cost rows
#define NBLK32 130              // 32-step blocks (tj 0..4159)
#define NWG    16

typedef __bf16 bf16x8 __attribute__((ext_vector_type(8)));
typedef float f32x4 __attribute__((ext_vector_type(4)));

#define CFENCE asm volatile("" ::: "memory")

__device__ __forceinline__ unsigned short f2bf(float f) {
    __hip_bfloat16 h = __float2bfloat16(f);
    return *reinterpret_cast<unsigned short*>(&h);
}

__device__ __forceinline__ void gll16(const void* gsrc, void* ldst) {
    __builtin_amdgcn_global_load_lds(
        (const __attribute__((address_space(1))) void*)gsrc,
        (__attribute__((address_space(3))) void*)ldst, 16, 0, 0);
}

// ---------------------------------------------------------------------------
// Kernel 1: row-normalize both trajectories, emit bf16
// ---------------------------------------------------------------------------
__global__ __launch_bounds__(256) void normalize_bf16(
    const float* __restrict__ t1, const float* __restrict__ t2,
    unsigned short* __restrict__ o1, unsigned short* __restrict__ o2)
{
    int b = blockIdx.x;
    int t = threadIdx.x;
    const float* src;
    unsigned short* dst;
    if (b < NROW) { src = t1 + (size_t)b * KDIM;          dst = o1 + (size_t)b * KDIM; }
    else          { src = t2 + (size_t)(b - NROW) * KDIM; dst = o2 + (size_t)(b - NROW) * KDIM; }

    float4 v = reinterpret_cast<const float4*>(src)[t];
    float ss = v.x * v.x + v.y * v.y + v.z * v.z + v.w * v.w;
    #pragma unroll
    for (int d = 32; d >= 1; d >>= 1) ss += __shfl_xor(ss, d, 64);

    __shared__ float wsum[4];
    int wave = t >> 6;
    if ((t & 63) == 0) wsum[wave] = ss;
    __syncthreads();
    float inv = 1.0f / (sqrtf(wsum[0] + wsum[1] + wsum[2] + wsum[3]) + 1e-8f);

    ushort4 o;
    o.x = f2bf(v.x * inv);
    o.y = f2bf(v.y * inv);
    o.z = f2bf(v.z * inv);
    o.w = f2bf(v.w * inv);
    reinterpret_cast<ushort4*>(dst)[t] = o;
}

// ---------------------------------------------------------------------------
// Kernel 2: skewed cost: skew[i + ((j>>2)&63)][j] = 1 - dot(t1n[i], t2n[j])
// ---------------------------------------------------------------------------
__global__ __launch_bounds__(256) void gemm_cost(
    const unsigned short* __restrict__ A,
    const unsigned short* __restrict__ B,
    unsigned short* __restrict__ Cs)    // skewed [SKROWS][4096]
{
    __shared__ __align__(16) unsigned short As[BM * BK];
    __shared__ __align__(16) unsigned short Bs[BM * BK];

    int t    = threadIdx.x;
    int lane = t & 63;
    int wave = t >> 6;
    int i0   = blockIdx.y * BM;
    int j0   = blockIdx.x * BM;

    f32x4 acc[4][4];
    f32x4 zero = {0.f, 0.f, 0.f, 0.f};
    #pragma unroll
    for (int m = 0; m < 4; ++m)
        #pragma unroll
        for (int n = 0; n < 4; ++n) acc[m][n] = zero;

    int frow = lane & 15;
    int fk   = (lane >> 4) * 8;
    int wr   = (wave >> 1) * 64;
    int wc   = (wave & 1) * 64;

    int srow = t >> 2;
    int scb  = (t & 3) * 8;

    uint4 ra0, ra1, rb0, rb1;
    {
        ra0 = *reinterpret_cast<const uint4*>(A + (size_t)(i0 + srow) * KDIM + scb);
        ra1 = *reinterpret_cast<const uint4*>(A + (size_t)(i0 + 64 + srow) * KDIM + scb);
        rb0 = *reinterpret_cast<const uint4*>(B + (size_t)(j0 + srow) * KDIM + scb);
        rb1 = *reinterpret_cast<const uint4*>(B + (size_t)(j0 + 64 + srow) * KDIM + scb);
    }

    for (int k0 = 0; k0 < KDIM; k0 += BK) {
        __syncthreads();
        *reinterpret_cast<uint4*>(As + (size_t)t * 8)         = ra0;
        *reinterpret_cast<uint4*>(As + (size_t)(256 + t) * 8) = ra1;
        *reinterpret_cast<uint4*>(Bs + (size_t)t * 8)         = rb0;
        *reinterpret_cast<uint4*>(Bs + (size_t)(256 + t) * 8) = rb1;
        __syncthreads();

        if (k0 + BK < KDIM) {
            int kn = k0 + BK;
            ra0 = *reinterpret_cast<const uint4*>(A + (size_t)(i0 + srow) * KDIM + kn + scb);
            ra1 = *reinterpret_cast<const uint4*>(A + (size_t)(i0 + 64 + srow) * KDIM + kn + scb);
            rb0 = *reinterpret_cast<const uint4*>(B + (size_t)(j0 + srow) * KDIM + kn + scb);
            rb1 = *reinterpret_cast<const uint4*>(B + (size_t)(j0 + 64 + srow) * KDIM + kn + scb);
        }

        bf16x8 af[4], bfr[4];
        #pragma unroll
        for (int m = 0; m < 4; ++m)
            af[m] = *reinterpret_cast<const bf16x8*>(As + (wr + m * 16 + frow) * BK + fk);
        #pragma unroll
        for (int n = 0; n < 4; ++n)
            bfr[n] = *reinterpret_cast<const bf16x8*>(Bs + (wc + n * 16 + frow) * BK + fk);

        #pragma unroll
        for (int m = 0; m < 4; ++m)
            #pragma unroll
            for (int n = 0; n < 4; ++n)
                acc[m][n] = __builtin_amdgcn_mfma_f32_16x16x32_bf16(af[m], bfr[n], acc[m][n], 0, 0, 0);
    }

    int crow = (lane >> 4) * 4;
    int ccol = lane & 15;
    #pragma unroll
    for (int n = 0; n < 4; ++n) {
        const int j  = j0 + wc + n * 16 + ccol;
        const int Lj = (j >> 2) & 63;
        #pragma unroll
        for (int m = 0; m < 4; ++m) {
            const int ibase = i0 + wr + m * 16 + crow;
            #pragma unroll
            for (int q = 0; q < 4; ++q)
                Cs[(size_t)(ibase + q + Lj) * NCOL + j] = f2bf(1.0f - acc[m][n][q]);
        }
    }
}

// ---------------------------------------------------------------------------
// ring_init: prefill dummy segment (index 15): tag = row+1, value = +INF.
// Read by WG 0 (real) and by ALL WGs in diag modes (always-valid tags).
// ---------------------------------------------------------------------------
__global__ __launch_bounds__(256) void ring_init(unsigned long long* __restrict__ ring)
{
    int i = blockIdx.x * 256 + threadIdx.x;
    ring[(size_t)15 * NROW + i] =
        ((unsigned long long)INFBITS << 32) | (unsigned)(i + 1);
}

// ---------------------------------------------------------------------------
// Kernel 3: systolic DTW, 16 WGs x 1 wave, free-running, 32-row blocks.
// Template ablation (measurement round):
//   DIAG=0: real (130 blocks). Tail slot-race fixed: staging SLOT comes from
//           the UNCLAMPED block id, so the clamped last prefetch can't land
//           in the slot being read (R8/R14 bug class).
//   DIAG=1: all WGs read the dummy tag segment (always valid -> no polls,
//           no coupling; identical instruction stream). 260 blocks so it
//           lands in rocprof's top-5 iff per-block c >= ~1.65us.
//   DIAG=2: additionally no gll staging (vmcnt(2)); pure VALU+ds_read body.
//           520 blocks -> visible iff c_valu >= ~0.85us.
// ---------------------------------------------------------------------------
template<int DIAG>
__global__ __launch_bounds__(64, 1) void dtw_systolic(
    const unsigned short* __restrict__ cost,   // skewed [SKROWS][4096]
    unsigned long long* __restrict__ ring,     // [16][4096] + garb[16][64]
    float* __restrict__ out)
{
    __shared__ __align__(16) unsigned char clds[2 * 16384];  // cost double-buffer
    __shared__ float outT[32];     // lane63's row-values for this block
    __shared__ float outD[64];     // per-lane dump (conflict-free)

    const int NBLKD = (DIAG == 0) ? NBLK32 : ((DIAG == 1) ? 260 : 520);
    const int w    = blockIdx.x;
    const int lane = threadIdx.x;
    const char* skewb = (const char*)cost;
    const unsigned long long* rseg = (DIAG == 0)
        ? (ring + (size_t)((w == 0) ? 15 : (w - 1)) * NROW)
        : (ring + (size_t)15 * NROW);
    unsigned long long* wseg = ring + (size_t)w * NROW;
    unsigned long long* garb = ring + (size_t)NWG * NROW + w * 64;
    const unsigned l32 = (unsigned)(lane & 31);
    const unsigned stripeByte = (unsigned)w * 512u + ((unsigned)(lane & 31) << 4);

    float pd0 = INFV, pd1 = INFV, pd2 = INFV, pd3 = INFV;
    float lprev = (w == 0 && lane == 0) ? 0.0f : INFV;   // DP origin seed
    float d3p = INFV;
    unsigned ansb = INFBITS;
    unsigned long long rv0 = 0, rv1 = 0, rv2 = 0;

// stage 32 rows of block STG into slot SLOT; rows clamped, slot explicit
#define GLL16S(STG, SLOT) { const int stg_ = (STG); \
    unsigned char* ldsb_ = clds + (SLOT) * 16384; \
    _Pragma("unroll") \
    for (int g_ = 0; g_ < 16; ++g_) { \
        int sr_ = 32 * stg_ + 2 * g_ + (lane >> 5); \
        if (sr_ > SKROWS - 1) sr_ = SKROWS - 1; \
        gll16(skewb + (size_t)sr_ * 8192 + stripeByte, ldsb_ + g_ * 1024); } }

// asm tag/value preload: invisible to compiler waitcnt pass, L2-bypass
#define RINGLD(DST, BI) { int pb_ = (BI); pb_ = pb_ < 0 ? 0 : (pb_ > 127 ? 127 : pb_); \
    const unsigned off_ = (32u * (unsigned)pb_ + l32) * 8u; \
    asm volatile("global_load_dwordx2 %0, %1, %2 sc0 sc1" \
                 : "=v"(DST) : "v"(off_), "s"(rseg) : "memory"); }

// pure-VALU step; lane63 records e3 in outT[K], others dump to own slot
#define DCOMP(K, CU) { \
    const unsigned rbK = (unsigned)__builtin_amdgcn_readlane(rvhi, (K)); \
    const float lcur = __uint_as_float((unsigned)__builtin_amdgcn_update_dpp( \
        (int)rbK, (int)__float_as_uint(d3p), 0x138, 0xf, 0xf, false)); \
    const float c0 = __uint_as_float(CU.x << 16); \
    const float c1 = __uint_as_float(CU.x & 0xffff0000u); \
    const float c2 = __uint_as_float(CU.y << 16); \
    const float c3 = __uint_as_float(CU.y & 0xffff0000u); \
    const float n0 = c0 + fminf(pd0, lprev); \
    const float n1 = c1 + fminf(pd1, pd0); \
    const float n2 = c2 + fminf(pd2, pd1); \
    const float n3 = c3 + fminf(pd3, pd2); \
    const float e0 = fminf(lcur + c0, n0); \
    const float e1 = fminf(e0 + c1, n1); \
    const float e2 = fminf(e1 + c2, n2); \
    const float e3 = fminf(e2 + c3, n3); \
    float* sp_ = (lane == 63) ? &outT[K] : &outD[lane]; \
    *sp_ = e3; \
    ansb = (tjb + (K) == 4158) ? __float_as_uint(e3) : ansb; \
    lprev = lcur; d3p = e3; \
    pd0 = e0; pd1 = e1; pd2 = e2; pd3 = e3; }

    // prologue: stage block 0 -> slot 0, preload tags for blocks 0..2
    if (DIAG != 2) { GLL16S(0, 0) }
    RINGLD(rv0, 0) RINGLD(rv1, 1) RINGLD(rv2, 2)
    CFENCE;

    #pragma unroll 1
    for (int ib = 0; ib < NBLKD; ++ib) {
        if (DIAG != 2) { GLL16S(ib + 1, (ib + 1) & 1) }  // slot from UNCLAMPED id
        unsigned long long rvN;
        RINGLD(rvN, ib + 3)
        CFENCE;
        if (DIAG != 2) {
            // forces prev block's 16 glls (read slot) + transitively rv0
            asm volatile("s_waitcnt vmcnt(19)" : "+v"(rv0) :: "memory");
        } else {
            asm volatile("s_waitcnt vmcnt(2)" : "+v"(rv0) :: "memory");
        }

        // tag check for this block (rows 32ib..32ib+31)
        if (ib < 128) {
            const unsigned expt = 32u * (unsigned)ib + l32 + 1u;
            while (__ballot((unsigned)rv0 == expt) != ~0ull)
                rv0 = __hip_atomic_load(rseg + 32u * (unsigned)ib + l32,
                                        __ATOMIC_RELAXED, __HIP_MEMORY_SCOPE_AGENT);
        }
        const int rvhi = (int)(unsigned)(rv0 >> 32);

        // batch-load the 32 cost uint2s into named regs
        const uint2* lu = reinterpret_cast<const uint2*>(
            clds + (ib & 1) * 16384 + (lane << 3));
        const uint2 cc0  = lu[0 * 64],  cc1  = lu[1 * 64];
        const uint2 cc2  = lu[2 * 64],  cc3  = lu[3 * 64];
        const uint2 cc4  = lu[4 * 64],  cc5  = lu[5 * 64];
        const uint2 cc6  = lu[6 * 64],  cc7  = lu[7 * 64];
        const uint2 cc8  = lu[8 * 64],  cc9  = lu[9 * 64];
        const uint2 cc10 = lu[10 * 64], cc11 = lu[11 * 64];
        const uint2 cc12 = lu[12 * 64], cc13 = lu[13 * 64];
        const uint2 cc14 = lu[14 * 64], cc15 = lu[15 * 64];
        const uint2 cc16 = lu[16 * 64], cc17 = lu[17 * 64];
        const uint2 cc18 = lu[18 * 64], cc19 = lu[19 * 64];
        const uint2 cc20 = lu[20 * 64], cc21 = lu[21 * 64];
        const uint2 cc22 = lu[22 * 64], cc23 = lu[23 * 64];
        const uint2 cc24 = lu[24 * 64], cc25 = lu[25 * 64];
        const uint2 cc26 = lu[26 * 64], cc27 = lu[27 * 64];
        const uint2 cc28 = lu[28 * 64], cc29 = lu[29 * 64];
        const uint2 cc30 = lu[30 * 64], cc31 = lu[31 * 64];

        const int rowbase = 32 * ib - 63;
        const int tjb = 32 * ib;

        DCOMP(0,  cc0)  DCOMP(1,  cc1)  DCOMP(2,  cc2)  DCOMP(3,  cc3)
        DCOMP(4,  cc4)  DCOMP(5,  cc5)  DCOMP(6,  cc6)  DCOMP(7,  cc7)
        DCOMP(8,  cc8)  DCOMP(9,  cc9)  DCOMP(10, cc10) DCOMP(11, cc11)
        DCOMP(12, cc12) DCOMP(13, cc13) DCOMP(14, cc14) DCOMP(15, cc15)
        DCOMP(16, cc16) DCOMP(17, cc17) DCOMP(18, cc18) DCOMP(19, cc19)
        DCOMP(20, cc20) DCOMP(21, cc21) DCOMP(22, cc22) DCOMP(23, cc23)
        DCOMP(24, cc24) DCOMP(25, cc25) DCOMP(26, cc26) DCOMP(27, cc27)
        DCOMP(28, cc28) DCOMP(29, cc29) DCOMP(30, cc30) DCOMP(31, cc31)

        // publish 32 boundary rows (lane k -> row rowbase+k), garb if invalid
        {
            const float bv = outT[l32];
            const int r = rowbase + (int)l32;
            const bool valid = (DIAG == 0) && (lane < 32) && (r >= 0) &&
                               (r <= 4095) && (w < NWG - 1);
            if (lane < 32) {
                const unsigned long long pk =
                    ((unsigned long long)__float_as_uint(bv) << 32) | (unsigned)(r + 1);
                unsigned long long* sp = valid ? (wseg + r) : (garb + lane);
                (void)__hip_atomic_exchange(sp, pk, __ATOMIC_RELAXED,
                                            __HIP_MEMORY_SCOPE_AGENT);
            }
        }
        CFENCE;

        rv0 = rv1; rv1 = rv2; rv2 = rvN;
    }

#undef GLL16S
#undef RINGLD
#undef DCOMP

    if (DIAG == 0 && w == NWG - 1 && lane == 63)
        out[0] = 1.0f / (1.0f + __uint_as_float(ansb));
}

// ---------------------------------------------------------------------------
extern "C" void kernel_launch(void* const* d_in, const int* in_sizes, int n_in,
                              void* d_out, int out_size, void* d_ws, size_t ws_size,
                              hipStream_t stream)
{
    const float* t1 = (const float*)d_in[0];
    const float* t2 = (const float*)d_in[1];
    float* out = (float*)d_out;

    char* ws = (char*)d_ws;
    unsigned short* t1n  = (unsigned short*)ws;                                   // 8 MB
    unsigned short* t2n  = (unsigned short*)(ws + (size_t)NROW * KDIM * 2);       // 8 MB
    unsigned short* skew = (unsigned short*)(ws + (size_t)16 * 1024 * 1024);      // 34.1 MB
    unsigned long long* ring = (unsigned long long*)(ws + (size_t)52 * 1024 * 1024);
    // ring: segs 0..14 real interfaces, seg 15 = dummy-INF, 16x64 garb

    hipMemsetAsync(ring, 0, (size_t)15 * NROW * 8, stream);
    ring_init<<<NROW / 256, 256, 0, stream>>>(ring);
    normalize_bf16<<<2 * NROW, 256, 0, stream>>>(t1, t2, t1n, t2n);
    gemm_cost<<<dim3(NCOL / BM, NROW / BM), 256, 0, stream>>>(t1n, t2n, skew);
    dtw_systolic<0><<<NWG, 64, 0, stream>>>(skew, ring, out);   // real
    dtw_systolic<1><<<NWG, 64, 0, stream>>>(skew, ring, out);   // no-coupling x260
    dtw_systolic<2><<<NWG, 64, 0, stream>>>(skew, ring, out);   // valu-only x520
}

// Round 18
// 598.692 us; speedup vs baseline: 3.4860x; 3.4860x over previous
//
#include <hip/hip_runtime.h>
#include <hip/hip_bf16.h>
#include <stdint.h>

#define KDIM 1024
#define NROW 4096
#define NCOL 4096
#define INFV 1e30f
#define INFBITS 0x7149F2CAu     // bits of 1e30f
#define BM 128
#define BK 32

#define SKROWS 4160             // skewed cost rows
#define NBLK32 130              // 32-step blocks (tj 0..4159)
#define NWG    16

typedef __bf16 bf16x8 __attribute__((ext_vector_type(8)));
typedef float f32x4 __attribute__((ext_vector_type(4)));

#define CFENCE asm volatile("" ::: "memory")

__device__ __forceinline__ unsigned short f2bf(float f) {
    __hip_bfloat16 h = __float2bfloat16(f);
    return *reinterpret_cast<unsigned short*>(&h);
}

__device__ __forceinline__ void gll16(const void* gsrc, void* ldst) {
    __builtin_amdgcn_global_load_lds(
        (const __attribute__((address_space(1))) void*)gsrc,
        (__attribute__((address_space(3))) void*)ldst, 16, 0, 0);
}

// ---------------------------------------------------------------------------
// Kernel 1: row-normalize both trajectories, emit bf16
// ---------------------------------------------------------------------------
__global__ __launch_bounds__(256) void normalize_bf16(
    const float* __restrict__ t1, const float* __restrict__ t2,
    unsigned short* __restrict__ o1, unsigned short* __restrict__ o2)
{
    int b = blockIdx.x;
    int t = threadIdx.x;
    const float* src;
    unsigned short* dst;
    if (b < NROW) { src = t1 + (size_t)b * KDIM;          dst = o1 + (size_t)b * KDIM; }
    else          { src = t2 + (size_t)(b - NROW) * KDIM; dst = o2 + (size_t)(b - NROW) * KDIM; }

    float4 v = reinterpret_cast<const float4*>(src)[t];
    float ss = v.x * v.x + v.y * v.y + v.z * v.z + v.w * v.w;
    #pragma unroll
    for (int d = 32; d >= 1; d >>= 1) ss += __shfl_xor(ss, d, 64);

    __shared__ float wsum[4];
    int wave = t >> 6;
    if ((t & 63) == 0) wsum[wave] = ss;
    __syncthreads();
    float inv = 1.0f / (sqrtf(wsum[0] + wsum[1] + wsum[2] + wsum[3]) + 1e-8f);

    ushort4 o;
    o.x = f2bf(v.x * inv);
    o.y = f2bf(v.y * inv);
    o.z = f2bf(v.z * inv);
    o.w = f2bf(v.w * inv);
    reinterpret_cast<ushort4*>(dst)[t] = o;
}

// ---------------------------------------------------------------------------
// Kernel 2: skewed cost: skew[i + ((j>>2)&63)][j] = 1 - dot(t1n[i], t2n[j])
// ---------------------------------------------------------------------------
__global__ __launch_bounds__(256) void gemm_cost(
    const unsigned short* __restrict__ A,
    const unsigned short* __restrict__ B,
    unsigned short* __restrict__ Cs)    // skewed [SKROWS][4096]
{
    __shared__ __align__(16) unsigned short As[BM * BK];
    __shared__ __align__(16) unsigned short Bs[BM * BK];

    int t    = threadIdx.x;
    int lane = t & 63;
    int wave = t >> 6;
    int i0   = blockIdx.y * BM;
    int j0   = blockIdx.x * BM;

    f32x4 acc[4][4];
    f32x4 zero = {0.f, 0.f, 0.f, 0.f};
    #pragma unroll
    for (int m = 0; m < 4; ++m)
        #pragma unroll
        for (int n = 0; n < 4; ++n) acc[m][n] = zero;

    int frow = lane & 15;
    int fk   = (lane >> 4) * 8;
    int wr   = (wave >> 1) * 64;
    int wc   = (wave & 1) * 64;

    int srow = t >> 2;
    int scb  = (t & 3) * 8;

    uint4 ra0, ra1, rb0, rb1;
    {
        ra0 = *reinterpret_cast<const uint4*>(A + (size_t)(i0 + srow) * KDIM + scb);
        ra1 = *reinterpret_cast<const uint4*>(A + (size_t)(i0 + 64 + srow) * KDIM + scb);
        rb0 = *reinterpret_cast<const uint4*>(B + (size_t)(j0 + srow) * KDIM + scb);
        rb1 = *reinterpret_cast<const uint4*>(B + (size_t)(j0 + 64 + srow) * KDIM + scb);
    }

    for (int k0 = 0; k0 < KDIM; k0 += BK) {
        __syncthreads();
        *reinterpret_cast<uint4*>(As + (size_t)t * 8)         = ra0;
        *reinterpret_cast<uint4*>(As + (size_t)(256 + t) * 8) = ra1;
        *reinterpret_cast<uint4*>(Bs + (size_t)t * 8)         = rb0;
        *reinterpret_cast<uint4*>(Bs + (size_t)(256 + t) * 8) = rb1;
        __syncthreads();

        if (k0 + BK < KDIM) {
            int kn = k0 + BK;
            ra0 = *reinterpret_cast<const uint4*>(A + (size_t)(i0 + srow) * KDIM + kn + scb);
            ra1 = *reinterpret_cast<const uint4*>(A + (size_t)(i0 + 64 + srow) * KDIM + kn + scb);
            rb0 = *reinterpret_cast<const uint4*>(B + (size_t)(j0 + srow) * KDIM + kn + scb);
            rb1 = *reinterpret_cast<const uint4*>(B + (size_t)(j0 + 64 + srow) * KDIM + kn + scb);
        }

        bf16x8 af[4], bfr[4];
        #pragma unroll
        for (int m = 0; m < 4; ++m)
            af[m] = *reinterpret_cast<const bf16x8*>(As + (wr + m * 16 + frow) * BK + fk);
        #pragma unroll
        for (int n = 0; n < 4; ++n)
            bfr[n] = *reinterpret_cast<const bf16x8*>(Bs + (wc + n * 16 + frow) * BK + fk);

        #pragma unroll
        for (int m = 0; m < 4; ++m)
            #pragma unroll
            for (int n = 0; n < 4; ++n)
                acc[m][n] = __builtin_amdgcn_mfma_f32_16x16x32_bf16(af[m], bfr[n], acc[m][n], 0, 0, 0);
    }

    int crow = (lane >> 4) * 4;
    int ccol = lane & 15;
    #pragma unroll
    for (int n = 0; n < 4; ++n) {
        const int j  = j0 + wc + n * 16 + ccol;
        const int Lj = (j >> 2) & 63;
        #pragma unroll
        for (int m = 0; m < 4; ++m) {
            const int ibase = i0 + wr + m * 16 + crow;
            #pragma unroll
            for (int q = 0; q < 4; ++q)
                Cs[(size_t)(ibase + q + Lj) * NCOL + j] = f2bf(1.0f - acc[m][n][q]);
        }
    }
}

// ---------------------------------------------------------------------------
// ring_init: prefill dummy segment (index 15): tag = row+1, value = +INF.
// ---------------------------------------------------------------------------
__global__ __launch_bounds__(256) void ring_init(unsigned long long* __restrict__ ring)
{
    int i = blockIdx.x * 256 + threadIdx.x;
    ring[(size_t)15 * NROW + i] =
        ((unsigned long long)INFBITS << 32) | (unsigned)(i + 1);
}

// ---------------------------------------------------------------------------
// Kernel 3: systolic DTW, 16 WGs x 1 wave, free-running, 32-row blocks.
// R16 ablation: body was chain-bound (DPP + 8 dependent fmin/add per row =
// 61 ns/row with zero staging/coupling). Fix: min-plus closed form per
// 4-col cell (same identity the reference uses: cummin(a-S)+S):
//   C_k = prefix-sum(c), n_k as before, u_k = n_k - C_k, m_k = cummin(u),
//   e_k = C_k + min(lcur, m_k).
// The lcur->e3 chain is now min+add (2 ops) after the DPP; the ~29 other
// VALU ops per row are issue-parallel. Staging/coupling unchanged (R14
// free-running structure + R16 slot-race fix).
// ---------------------------------------------------------------------------
__global__ __launch_bounds__(64, 1) void dtw_systolic(
    const unsigned short* __restrict__ cost,   // skewed [SKROWS][4096]
    unsigned long long* __restrict__ ring,     // [16][4096] + garb[16][64]
    float* __restrict__ out)
{
    __shared__ __align__(16) unsigned char clds[2 * 16384];  // cost double-buffer
    __shared__ float outT[32];     // lane63's row-values for this block
    __shared__ float outD[64];     // per-lane dump (conflict-free)

    const int w    = blockIdx.x;
    const int lane = threadIdx.x;
    const char* skewb = (const char*)cost;
    const unsigned long long* rseg = ring + (size_t)((w == 0) ? 15 : (w - 1)) * NROW;
    unsigned long long* wseg = ring + (size_t)w * NROW;
    unsigned long long* garb = ring + (size_t)NWG * NROW + w * 64;
    const unsigned l32 = (unsigned)(lane & 31);
    const unsigned stripeByte = (unsigned)w * 512u + ((unsigned)(lane & 31) << 4);

    float pd0 = INFV, pd1 = INFV, pd2 = INFV, pd3 = INFV;
    float lprev = (w == 0 && lane == 0) ? 0.0f : INFV;   // DP origin seed
    float d3p = INFV;
    unsigned ansb = INFBITS;
    unsigned long long rv0 = 0, rv1 = 0, rv2 = 0;

// stage 32 rows of block STG into slot SLOT; rows clamped, slot from
// UNCLAMPED id at the call site (R8/R14 race fix)
#define GLL16S(STG, SLOT) { const int stg_ = (STG); \
    unsigned char* ldsb_ = clds + (SLOT) * 16384; \
    _Pragma("unroll") \
    for (int g_ = 0; g_ < 16; ++g_) { \
        int sr_ = 32 * stg_ + 2 * g_ + (lane >> 5); \
        if (sr_ > SKROWS - 1) sr_ = SKROWS - 1; \
        gll16(skewb + (size_t)sr_ * 8192 + stripeByte, ldsb_ + g_ * 1024); } }

// asm tag/value preload: invisible to compiler waitcnt pass, L2-bypass
#define RINGLD(DST, BI) { int pb_ = (BI); pb_ = pb_ < 0 ? 0 : (pb_ > 127 ? 127 : pb_); \
    const unsigned off_ = (32u * (unsigned)pb_ + l32) * 8u; \
    asm volatile("global_load_dwordx2 %0, %1, %2 sc0 sc1" \
                 : "=v"(DST) : "v"(off_), "s"(rseg) : "memory"); }

// closed-form step: chain = DPP -> fmin -> add; rest issue-parallel
#define DCOMP(K, CU) { \
    const unsigned rbK = (unsigned)__builtin_amdgcn_readlane(rvhi, (K)); \
    const float c0 = __uint_as_float(CU.x << 16); \
    const float c1 = __uint_as_float(CU.x & 0xffff0000u); \
    const float c2 = __uint_as_float(CU.y << 16); \
    const float c3 = __uint_as_float(CU.y & 0xffff0000u); \
    const float n0 = c0 + fminf(pd0, lprev); \
    const float n1 = c1 + fminf(pd1, pd0); \
    const float n2 = c2 + fminf(pd2, pd1); \
    const float n3 = c3 + fminf(pd3, pd2); \
    const float C1 = c0 + c1; \
    const float C2 = C1 + c2; \
    const float C3 = C2 + c3; \
    const float u0 = n0 - c0; \
    const float u1 = n1 - C1; \
    const float u2 = n2 - C2; \
    const float u3 = n3 - C3; \
    const float m1 = fminf(u0, u1); \
    const float m2 = fminf(m1, u2); \
    const float m3 = fminf(m2, u3); \
    const float lcur = __uint_as_float((unsigned)__builtin_amdgcn_update_dpp( \
        (int)rbK, (int)__float_as_uint(d3p), 0x138, 0xf, 0xf, false)); \
    pd0 = c0 + fminf(lcur, u0); \
    pd1 = C1 + fminf(lcur, m1); \
    pd2 = C2 + fminf(lcur, m2); \
    pd3 = C3 + fminf(lcur, m3); \
    float* sp_ = (lane == 63) ? &outT[K] : &outD[lane]; \
    *sp_ = pd3; \
    ansb = (tjb + (K) == 4158) ? __float_as_uint(pd3) : ansb; \
    lprev = lcur; d3p = pd3; }

    // prologue: stage block 0 -> slot 0, preload tags for blocks 0..2
    GLL16S(0, 0)
    RINGLD(rv0, 0) RINGLD(rv1, 1) RINGLD(rv2, 2)
    CFENCE;

    #pragma unroll 1
    for (int ib = 0; ib < NBLK32; ++ib) {
        GLL16S(ib + 1, (ib + 1) & 1)       // slot from UNCLAMPED id
        unsigned long long rvN;
        RINGLD(rvN, ib + 3)
        CFENCE;
        // forces prev block's 16 glls (read slot) + transitively rv0
        asm volatile("s_waitcnt vmcnt(19)" : "+v"(rv0) :: "memory");

        // tag check for this block (rows 32ib..32ib+31)
        if (ib < 128) {
            const unsigned expt = 32u * (unsigned)ib + l32 + 1u;
            while (__ballot((unsigned)rv0 == expt) != ~0ull)
                rv0 = __hip_atomic_load(rseg + 32u * (unsigned)ib + l32,
                                        __ATOMIC_RELAXED, __HIP_MEMORY_SCOPE_AGENT);
        }
        const int rvhi = (int)(unsigned)(rv0 >> 32);

        // batch-load the 32 cost uint2s into named regs
        const uint2* lu = reinterpret_cast<const uint2*>(
            clds + (ib & 1) * 16384 + (lane << 3));
        const uint2 cc0  = lu[0 * 64],  cc1  = lu[1 * 64];
        const uint2 cc2  = lu[2 * 64],  cc3  = lu[3 * 64];
        const uint2 cc4  = lu[4 * 64],  cc5  = lu[5 * 64];
        const uint2 cc6  = lu[6 * 64],  cc7  = lu[7 * 64];
        const uint2 cc8  = lu[8 * 64],  cc9  = lu[9 * 64];
        const uint2 cc10 = lu[10 * 64], cc11 = lu[11 * 64];
        const uint2 cc12 = lu[12 * 64], cc13 = lu[13 * 64];
        const uint2 cc14 = lu[14 * 64], cc15 = lu[15 * 64];
        const uint2 cc16 = lu[16 * 64], cc17 = lu[17 * 64];
        const uint2 cc18 = lu[18 * 64], cc19 = lu[19 * 64];
        const uint2 cc20 = lu[20 * 64], cc21 = lu[21 * 64];
        const uint2 cc22 = lu[22 * 64], cc23 = lu[23 * 64];
        const uint2 cc24 = lu[24 * 64], cc25 = lu[25 * 64];
        const uint2 cc26 = lu[26 * 64], cc27 = lu[27 * 64];
        const uint2 cc28 = lu[28 * 64], cc29 = lu[29 * 64];
        const uint2 cc30 = lu[30 * 64], cc31 = lu[31 * 64];

        const int rowbase = 32 * ib - 63;
        const int tjb = 32 * ib;

        DCOMP(0,  cc0)  DCOMP(1,  cc1)  DCOMP(2,  cc2)  DCOMP(3,  cc3)
        DCOMP(4,  cc4)  DCOMP(5,  cc5)  DCOMP(6,  cc6)  DCOMP(7,  cc7)
        DCOMP(8,  cc8)  DCOMP(9,  cc9)  DCOMP(10, cc10) DCOMP(11, cc11)
        DCOMP(12, cc12) DCOMP(13, cc13) DCOMP(14, cc14) DCOMP(15, cc15)
        DCOMP(16, cc16) DCOMP(17, cc17) DCOMP(18, cc18) DCOMP(19, cc19)
        DCOMP(20, cc20) DCOMP(21, cc21) DCOMP(22, cc22) DCOMP(23, cc23)
        DCOMP(24, cc24) DCOMP(25, cc25) DCOMP(26, cc26) DCOMP(27, cc27)
        DCOMP(28, cc28) DCOMP(29, cc29) DCOMP(30, cc30) DCOMP(31, cc31)

        // publish 32 boundary rows (lane k -> row rowbase+k), garb if invalid
        {
            const float bv = outT[l32];
            const int r = rowbase + (int)l32;
            const bool valid = (lane < 32) && (r >= 0) && (r <= 4095) &&
                               (w < NWG - 1);
            if (lane < 32) {
                const unsigned long long pk =
                    ((unsigned long long)__float_as_uint(bv) << 32) | (unsigned)(r + 1);
                unsigned long long* sp = valid ? (wseg + r) : (garb + lane);
                (void)__hip_atomic_exchange(sp, pk, __ATOMIC_RELAXED,
                                            __HIP_MEMORY_SCOPE_AGENT);
            }
        }
        CFENCE;

        rv0 = rv1; rv1 = rv2; rv2 = rvN;
    }

#undef GLL16S
#undef RINGLD
#undef DCOMP

    if (w == NWG - 1 && lane == 63)
        out[0] = 1.0f / (1.0f + __uint_as_float(ansb));
}

// ---------------------------------------------------------------------------
extern "C" void kernel_launch(void* const* d_in, const int* in_sizes, int n_in,
                              void* d_out, int out_size, void* d_ws, size_t ws_size,
                              hipStream_t stream)
{
    const float* t1 = (const float*)d_in[0];
    const float* t2 = (const float*)d_in[1];
    float* out = (float*)d_out;

    char* ws = (char*)d_ws;
    unsigned short* t1n  = (unsigned short*)ws;                                   // 8 MB
    unsigned short* t2n  = (unsigned short*)(ws + (size_t)NROW * KDIM * 2);       // 8 MB
    unsigned short* skew = (unsigned short*)(ws + (size_t)16 * 1024 * 1024);      // 34.1 MB
    unsigned long long* ring = (unsigned long long*)(ws + (size_t)52 * 1024 * 1024);
    // ring: segs 0..14 real interfaces, seg 15 = dummy-INF, 16x64 garb

    hipMemsetAsync(ring, 0, (size_t)15 * NROW * 8, stream);
    ring_init<<<NROW / 256, 256, 0, stream>>>(ring);
    normalize_bf16<<<2 * NROW, 256, 0, stream>>>(t1, t2, t1n, t2n);
    gemm_cost<<<dim3(NCOL / BM, NROW / BM), 256, 0, stream>>>(t1n, t2n, skew);
    dtw_systolic<<<NWG, 64, 0, stream>>>(skew, ring, out);
}

// Round 19
// 537.249 us; speedup vs baseline: 3.8847x; 1.1144x over previous
//
#include <hip/hip_runtime.h>
#include <hip/hip_bf16.h>
#include <stdint.h>

#define KDIM 1024
#define NROW 4096
#define NCOL 4096
#define INFV 1e30f
#define INFBITS 0x7149F2CAu     // bits of 1e30f
#define BM 128
#define BK 32

#define SKROWS 4160             // skewed cost rows
#define NBLK32 130              // 32-step blocks (tj 0..4159)
#define NWG    16

typedef __bf16 bf16x8 __attribute__((ext_vector_type(8)));
typedef float f32x4 __attribute__((ext_vector_type(4)));

#define CFENCE asm volatile("" ::: "memory")

__device__ __forceinline__ unsigned short f2bf(float f) {
    __hip_bfloat16 h = __float2bfloat16(f);
    return *reinterpret_cast<unsigned short*>(&h);
}

__device__ __forceinline__ void gll16(const void* gsrc, void* ldst) {
    __builtin_amdgcn_global_load_lds(
        (const __attribute__((address_space(1))) void*)gsrc,
        (__attribute__((address_space(3))) void*)ldst, 16, 0, 0);
}

// ---------------------------------------------------------------------------
// Kernel 1: row-normalize both trajectories, emit bf16
// ---------------------------------------------------------------------------
__global__ __launch_bounds__(256) void normalize_bf16(
    const float* __restrict__ t1, const float* __restrict__ t2,
    unsigned short* __restrict__ o1, unsigned short* __restrict__ o2)
{
    int b = blockIdx.x;
    int t = threadIdx.x;
    const float* src;
    unsigned short* dst;
    if (b < NROW) { src = t1 + (size_t)b * KDIM;          dst = o1 + (size_t)b * KDIM; }
    else          { src = t2 + (size_t)(b - NROW) * KDIM; dst = o2 + (size_t)(b - NROW) * KDIM; }

    float4 v = reinterpret_cast<const float4*>(src)[t];
    float ss = v.x * v.x + v.y * v.y + v.z * v.z + v.w * v.w;
    #pragma unroll
    for (int d = 32; d >= 1; d >>= 1) ss += __shfl_xor(ss, d, 64);

    __shared__ float wsum[4];
    int wave = t >> 6;
    if ((t & 63) == 0) wsum[wave] = ss;
    __syncthreads();
    float inv = 1.0f / (sqrtf(wsum[0] + wsum[1] + wsum[2] + wsum[3]) + 1e-8f);

    ushort4 o;
    o.x = f2bf(v.x * inv);
    o.y = f2bf(v.y * inv);
    o.z = f2bf(v.z * inv);
    o.w = f2bf(v.w * inv);
    reinterpret_cast<ushort4*>(dst)[t] = o;
}

// ---------------------------------------------------------------------------
// Kernel 2: skewed cost: skew[i + ((j>>2)&63)][j] = 1 - dot(t1n[i], t2n[j])
// ---------------------------------------------------------------------------
__global__ __launch_bounds__(256) void gemm_cost(
    const unsigned short* __restrict__ A,
    const unsigned short* __restrict__ B,
    unsigned short* __restrict__ Cs)    // skewed [SKROWS][4096]
{
    __shared__ __align__(16) unsigned short As[BM * BK];
    __shared__ __align__(16) unsigned short Bs[BM * BK];

    int t    = threadIdx.x;
    int lane = t & 63;
    int wave = t >> 6;
    int i0   = blockIdx.y * BM;
    int j0   = blockIdx.x * BM;

    f32x4 acc[4][4];
    f32x4 zero = {0.f, 0.f, 0.f, 0.f};
    #pragma unroll
    for (int m = 0; m < 4; ++m)
        #pragma unroll
        for (int n = 0; n < 4; ++n) acc[m][n] = zero;

    int frow = lane & 15;
    int fk   = (lane >> 4) * 8;
    int wr   = (wave >> 1) * 64;
    int wc   = (wave & 1) * 64;

    int srow = t >> 2;
    int scb  = (t & 3) * 8;

    uint4 ra0, ra1, rb0, rb1;
    {
        ra0 = *reinterpret_cast<const uint4*>(A + (size_t)(i0 + srow) * KDIM + scb);
        ra1 = *reinterpret_cast<const uint4*>(A + (size_t)(i0 + 64 + srow) * KDIM + scb);
        rb0 = *reinterpret_cast<const uint4*>(B + (size_t)(j0 + srow) * KDIM + scb);
        rb1 = *reinterpret_cast<const uint4*>(B + (size_t)(j0 + 64 + srow) * KDIM + scb);
    }

    for (int k0 = 0; k0 < KDIM; k0 += BK) {
        __syncthreads();
        *reinterpret_cast<uint4*>(As + (size_t)t * 8)         = ra0;
        *reinterpret_cast<uint4*>(As + (size_t)(256 + t) * 8) = ra1;
        *reinterpret_cast<uint4*>(Bs + (size_t)t * 8)         = rb0;
        *reinterpret_cast<uint4*>(Bs + (size_t)(256 + t) * 8) = rb1;
        __syncthreads();

        if (k0 + BK < KDIM) {
            int kn = k0 + BK;
            ra0 = *reinterpret_cast<const uint4*>(A + (size_t)(i0 + srow) * KDIM + kn + scb);
            ra1 = *reinterpret_cast<const uint4*>(A + (size_t)(i0 + 64 + srow) * KDIM + kn + scb);
            rb0 = *reinterpret_cast<const uint4*>(B + (size_t)(j0 + srow) * KDIM + kn + scb);
            rb1 = *reinterpret_cast<const uint4*>(B + (size_t)(j0 + 64 + srow) * KDIM + kn + scb);
        }

        bf16x8 af[4], bfr[4];
        #pragma unroll
        for (int m = 0; m < 4; ++m)
            af[m] = *reinterpret_cast<const bf16x8*>(As + (wr + m * 16 + frow) * BK + fk);
        #pragma unroll
        for (int n = 0; n < 4; ++n)
            bfr[n] = *reinterpret_cast<const bf16x8*>(Bs + (wc + n * 16 + frow) * BK + fk);

        #pragma unroll
        for (int m = 0; m < 4; ++m)
            #pragma unroll
            for (int n = 0; n < 4; ++n)
                acc[m][n] = __builtin_amdgcn_mfma_f32_16x16x32_bf16(af[m], bfr[n], acc[m][n], 0, 0, 0);
    }

    int crow = (lane >> 4) * 4;
    int ccol = lane & 15;
    #pragma unroll
    for (int n = 0; n < 4; ++n) {
        const int j  = j0 + wc + n * 16 + ccol;
        const int Lj = (j >> 2) & 63;
        #pragma unroll
        for (int m = 0; m < 4; ++m) {
            const int ibase = i0 + wr + m * 16 + crow;
            #pragma unroll
            for (int q = 0; q < 4; ++q)
                Cs[(size_t)(ibase + q + Lj) * NCOL + j] = f2bf(1.0f - acc[m][n][q]);
        }
    }
}

// ---------------------------------------------------------------------------
// ring_init: prefill dummy segment (index 15): tag = row+1, value = +INF.
// ---------------------------------------------------------------------------
__global__ __launch_bounds__(256) void ring_init(unsigned long long* __restrict__ ring)
{
    int i = blockIdx.x * 256 + threadIdx.x;
    ring[(size_t)15 * NROW + i] =
        ((unsigned long long)INFBITS << 32) | (unsigned)(i + 1);
}

// ---------------------------------------------------------------------------
// Kernel 3: systolic DTW, 16 WGs x 1 wave, free-running, 32-row blocks.
// Body rework (R17 failed: closed form moved the chain into n->u->m, +10
// issue). This version: u-substitution closed form with TREE-min
//   f_k = fmin(pd_k, pd_{k-1});  u_k = f_k - S_{k-1}  (S = c prefix sums)
//   pd_k' = S_k + fmin(lcur, min(u_0..u_k))   [tree: m01,m23,m012,m0123]
// chain from pd(prev) = 5-6 deps; issue ~30 ops/row. Boundary injection:
// bvec VGPR (lane k = ring row k value) rotated down 1 lane/row via DPP
// wave_shl:1, lane-0 select via one v_cndmask -> no per-row readlane/mov
// hazards. Output row values to outBlk[K][lane] (compile-time offset).
// Staging/coupling = R14 free-running structure + unclamped-slot fix.
// ---------------------------------------------------------------------------
__global__ __launch_bounds__(64, 1) void dtw_systolic(
    const unsigned short* __restrict__ cost,   // skewed [SKROWS][4096]
    unsigned long long* __restrict__ ring,     // [16][4096] + garb[16][64]
    float* __restrict__ out)
{
    __shared__ __align__(16) unsigned char clds[2 * 16384];  // cost double-buffer
    __shared__ float outBlk[32][64];   // row-values per block; col 63 = boundary

    const int w    = blockIdx.x;
    const int lane = threadIdx.x;
    const char* skewb = (const char*)cost;
    const unsigned long long* rseg = ring + (size_t)((w == 0) ? 15 : (w - 1)) * NROW;
    unsigned long long* wseg = ring + (size_t)w * NROW;
    unsigned long long* garb = ring + (size_t)NWG * NROW + w * 64;
    const unsigned l32 = (unsigned)(lane & 31);
    const unsigned stripeByte = (unsigned)w * 512u + ((unsigned)(lane & 31) << 4);
    const bool isl0 = (lane == 0);

    float pd0 = INFV, pd1 = INFV, pd2 = INFV, pd3 = INFV;
    float lprev = (w == 0 && lane == 0) ? 0.0f : INFV;   // DP origin seed
    float d3p = INFV;
    unsigned long long rv0 = 0, rv1 = 0, rv2 = 0;

// stage 32 rows of block STG into slot SLOT (slot from UNCLAMPED id at call)
#define GLL16S(STG, SLOT) { const int stg_ = (STG); \
    unsigned char* ldsb_ = clds + (SLOT) * 16384; \
    _Pragma("unroll") \
    for (int g_ = 0; g_ < 16; ++g_) { \
        int sr_ = 32 * stg_ + 2 * g_ + (lane >> 5); \
        if (sr_ > SKROWS - 1) sr_ = SKROWS - 1; \
        gll16(skewb + (size_t)sr_ * 8192 + stripeByte, ldsb_ + g_ * 1024); } }

// asm tag/value preload: invisible to compiler waitcnt pass, L2-bypass
#define RINGLD(DST, BI) { int pb_ = (BI); pb_ = pb_ < 0 ? 0 : (pb_ > 127 ? 127 : pb_); \
    const unsigned off_ = (32u * (unsigned)pb_ + l32) * 8u; \
    asm volatile("global_load_dwordx2 %0, %1, %2 sc0 sc1" \
                 : "=v"(DST) : "v"(off_), "s"(rseg) : "memory"); }

// closed-form step with tree-min; bvec carries boundary values (rotated)
#define DCOMP(K, CU) { \
    const float c0 = __uint_as_float(CU.x << 16); \
    const float c1 = __uint_as_float(CU.x & 0xffff0000u); \
    const float c2 = __uint_as_float(CU.y << 16); \
    const float c3 = __uint_as_float(CU.y & 0xffff0000u); \
    const float C1 = c0 + c1; \
    const float C2 = C1 + c2; \
    const float C3 = C2 + c3; \
    const float f0 = fminf(pd0, lprev); \
    const float f1 = fminf(pd1, pd0); \
    const float f2 = fminf(pd2, pd1); \
    const float f3 = fminf(pd3, pd2); \
    const float u1 = f1 - c0; \
    const float u2 = f2 - C1; \
    const float u3 = f3 - C2; \
    const float m01  = fminf(f0, u1); \
    const float m23  = fminf(u2, u3); \
    const float m012 = fminf(m01, u2); \
    const float m03  = fminf(m01, m23); \
    const float dsh = __uint_as_float((unsigned)__builtin_amdgcn_update_dpp( \
        0, (int)__float_as_uint(d3p), 0x138, 0xf, 0xf, true)); \
    const float lcur = isl0 ? __uint_as_float((unsigned)bvec) : dsh; \
    pd0 = c0 + fminf(lcur, f0); \
    pd1 = C1 + fminf(lcur, m01); \
    pd2 = C2 + fminf(lcur, m012); \
    pd3 = C3 + fminf(lcur, m03); \
    outBlk[K][lane] = pd3; \
    bvec = __builtin_amdgcn_update_dpp(0, bvec, 0x130, 0xf, 0xf, true); \
    lprev = lcur; d3p = pd3; }

    // prologue: stage block 0 -> slot 0, preload tags for blocks 0..2
    GLL16S(0, 0)
    RINGLD(rv0, 0) RINGLD(rv1, 1) RINGLD(rv2, 2)
    CFENCE;

    #pragma unroll 1
    for (int ib = 0; ib < NBLK32; ++ib) {
        GLL16S(ib + 1, (ib + 1) & 1)       // slot from UNCLAMPED id
        unsigned long long rvN;
        RINGLD(rvN, ib + 3)
        CFENCE;
        // forces prev block's 16 glls (read slot) + transitively rv0
        asm volatile("s_waitcnt vmcnt(19)" : "+v"(rv0) :: "memory");

        // tag check for this block (rows 32ib..32ib+31)
        if (ib < 128) {
            const unsigned expt = 32u * (unsigned)ib + l32 + 1u;
            while (__ballot((unsigned)rv0 == expt) != ~0ull)
                rv0 = __hip_atomic_load(rseg + 32u * (unsigned)ib + l32,
                                        __ATOMIC_RELAXED, __HIP_MEMORY_SCOPE_AGENT);
        }
        int bvec = (int)(unsigned)(rv0 >> 32);   // lane k = boundary row 32ib+k

        // batch-load the 32 cost uint2s into named regs
        const uint2* lu = reinterpret_cast<const uint2*>(
            clds + (ib & 1) * 16384 + (lane << 3));
        const uint2 cc0  = lu[0 * 64],  cc1  = lu[1 * 64];
        const uint2 cc2  = lu[2 * 64],  cc3  = lu[3 * 64];
        const uint2 cc4  = lu[4 * 64],  cc5  = lu[5 * 64];
        const uint2 cc6  = lu[6 * 64],  cc7  = lu[7 * 64];
        const uint2 cc8  = lu[8 * 64],  cc9  = lu[9 * 64];
        const uint2 cc10 = lu[10 * 64], cc11 = lu[11 * 64];
        const uint2 cc12 = lu[12 * 64], cc13 = lu[13 * 64];
        const uint2 cc14 = lu[14 * 64], cc15 = lu[15 * 64];
        const uint2 cc16 = lu[16 * 64], cc17 = lu[17 * 64];
        const uint2 cc18 = lu[18 * 64], cc19 = lu[19 * 64];
        const uint2 cc20 = lu[20 * 64], cc21 = lu[21 * 64];
        const uint2 cc22 = lu[22 * 64], cc23 = lu[23 * 64];
        const uint2 cc24 = lu[24 * 64], cc25 = lu[25 * 64];
        const uint2 cc26 = lu[26 * 64], cc27 = lu[27 * 64];
        const uint2 cc28 = lu[28 * 64], cc29 = lu[29 * 64];
        const uint2 cc30 = lu[30 * 64], cc31 = lu[31 * 64];

        DCOMP(0,  cc0)  DCOMP(1,  cc1)  DCOMP(2,  cc2)  DCOMP(3,  cc3)
        DCOMP(4,  cc4)  DCOMP(5,  cc5)  DCOMP(6,  cc6)  DCOMP(7,  cc7)
        DCOMP(8,  cc8)  DCOMP(9,  cc9)  DCOMP(10, cc10) DCOMP(11, cc11)
        DCOMP(12, cc12) DCOMP(13, cc13) DCOMP(14, cc14) DCOMP(15, cc15)
        DCOMP(16, cc16) DCOMP(17, cc17) DCOMP(18, cc18) DCOMP(19, cc19)
        DCOMP(20, cc20) DCOMP(21, cc21) DCOMP(22, cc22) DCOMP(23, cc23)
        DCOMP(24, cc24) DCOMP(25, cc25) DCOMP(26, cc26) DCOMP(27, cc27)
        DCOMP(28, cc28) DCOMP(29, cc29) DCOMP(30, cc30) DCOMP(31, cc31)

        // publish 32 boundary rows (lane k -> row rowbase+k), garb if invalid
        {
            const int rowbase = 32 * ib - 63;
            const float bv = outBlk[l32][63];
            const int r = rowbase + (int)l32;
            const bool valid = (lane < 32) && (r >= 0) && (r <= 4095) &&
                               (w < NWG - 1);
            if (lane < 32) {
                const unsigned long long pk =
                    ((unsigned long long)__float_as_uint(bv) << 32) | (unsigned)(r + 1);
                unsigned long long* sp = valid ? (wseg + r) : (garb + lane);
                (void)__hip_atomic_exchange(sp, pk, __ATOMIC_RELAXED,
                                            __HIP_MEMORY_SCOPE_AGENT);
            }
        }
        CFENCE;

        rv0 = rv1; rv1 = rv2; rv2 = rvN;
    }

#undef GLL16S
#undef RINGLD
#undef DCOMP

    // D[4095][4095] = block 129 (rowbase 4065), K=30, lane 63
    if (w == NWG - 1 && lane == 63)
        out[0] = 1.0f / (1.0f + outBlk[30][63]);
}

// ---------------------------------------------------------------------------
extern "C" void kernel_launch(void* const* d_in, const int* in_sizes, int n_in,
                              void* d_out, int out_size, void* d_ws, size_t ws_size,
                              hipStream_t stream)
{
    const float* t1 = (const float*)d_in[0];
    const float* t2 = (const float*)d_in[1];
    float* out = (float*)d_out;

    char* ws = (char*)d_ws;
    unsigned short* t1n  = (unsigned short*)ws;                                   // 8 MB
    unsigned short* t2n  = (unsigned short*)(ws + (size_t)NROW * KDIM * 2);       // 8 MB
    unsigned short* skew = (unsigned short*)(ws + (size_t)16 * 1024 * 1024);      // 34.1 MB
    unsigned long long* ring = (unsigned long long*)(ws + (size_t)52 * 1024 * 1024);
    // ring: segs 0..14 real interfaces, seg 15 = dummy-INF, 16x64 garb

    hipMemsetAsync(ring, 0, (size_t)15 * NROW * 8, stream);
    ring_init<<<NROW / 256, 256, 0, stream>>>(ring);
    normalize_bf16<<<2 * NROW, 256, 0, stream>>>(t1, t2, t1n, t2n);
    gemm_cost<<<dim3(NCOL / BM, NROW / BM), 256, 0, stream>>>(t1n, t2n, skew);
    dtw_systolic<<<NWG, 64, 0, stream>>>(skew, ring, out);
}

// Round 20
// 517.930 us; speedup vs baseline: 4.0296x; 1.0373x over previous
//
#include <hip/hip_runtime.h>
#include <hip/hip_bf16.h>
#include <stdint.h>

#define KDIM 1024
#define NROW 4096
#define NCOL 4096
#define INFV 1e30f
#define INFBITS 0x7149F2CAu     // bits of 1e30f
#define BM 128
#define BK 32

#define SKROWS 4160             // skewed cost rows
#define NBLK32 130              // 32-step blocks (tj 0..4159)
#define NWG    16

typedef __bf16 bf16x8 __attribute__((ext_vector_type(8)));
typedef float f32x4 __attribute__((ext_vector_type(4)));

#define CFENCE asm volatile("" ::: "memory")

__device__ __forceinline__ unsigned short f2bf(float f) {
    __hip_bfloat16 h = __float2bfloat16(f);
    return *reinterpret_cast<unsigned short*>(&h);
}

__device__ __forceinline__ void gll16(const void* gsrc, void* ldst) {
    __builtin_amdgcn_global_load_lds(
        (const __attribute__((address_space(1))) void*)gsrc,
        (__attribute__((address_space(3))) void*)ldst, 16, 0, 0);
}

// ---------------------------------------------------------------------------
// Kernel 1: row-normalize both trajectories, emit bf16
// ---------------------------------------------------------------------------
__global__ __launch_bounds__(256) void normalize_bf16(
    const float* __restrict__ t1, const float* __restrict__ t2,
    unsigned short* __restrict__ o1, unsigned short* __restrict__ o2)
{
    int b = blockIdx.x;
    int t = threadIdx.x;
    const float* src;
    unsigned short* dst;
    if (b < NROW) { src = t1 + (size_t)b * KDIM;          dst = o1 + (size_t)b * KDIM; }
    else          { src = t2 + (size_t)(b - NROW) * KDIM; dst = o2 + (size_t)(b - NROW) * KDIM; }

    float4 v = reinterpret_cast<const float4*>(src)[t];
    float ss = v.x * v.x + v.y * v.y + v.z * v.z + v.w * v.w;
    #pragma unroll
    for (int d = 32; d >= 1; d >>= 1) ss += __shfl_xor(ss, d, 64);

    __shared__ float wsum[4];
    int wave = t >> 6;
    if ((t & 63) == 0) wsum[wave] = ss;
    __syncthreads();
    float inv = 1.0f / (sqrtf(wsum[0] + wsum[1] + wsum[2] + wsum[3]) + 1e-8f);

    ushort4 o;
    o.x = f2bf(v.x * inv);
    o.y = f2bf(v.y * inv);
    o.z = f2bf(v.z * inv);
    o.w = f2bf(v.w * inv);
    reinterpret_cast<ushort4*>(dst)[t] = o;
}

// ---------------------------------------------------------------------------
// Kernel 2: skewed cost: skew[i + ((j>>2)&63)][j] = 1 - dot(t1n[i], t2n[j])
// ---------------------------------------------------------------------------
__global__ __launch_bounds__(256) void gemm_cost(
    const unsigned short* __restrict__ A,
    const unsigned short* __restrict__ B,
    unsigned short* __restrict__ Cs)    // skewed [SKROWS][4096]
{
    __shared__ __align__(16) unsigned short As[BM * BK];
    __shared__ __align__(16) unsigned short Bs[BM * BK];

    int t    = threadIdx.x;
    int lane = t & 63;
    int wave = t >> 6;
    int i0   = blockIdx.y * BM;
    int j0   = blockIdx.x * BM;

    f32x4 acc[4][4];
    f32x4 zero = {0.f, 0.f, 0.f, 0.f};
    #pragma unroll
    for (int m = 0; m < 4; ++m)
        #pragma unroll
        for (int n = 0; n < 4; ++n) acc[m][n] = zero;

    int frow = lane & 15;
    int fk   = (lane >> 4) * 8;
    int wr   = (wave >> 1) * 64;
    int wc   = (wave & 1) * 64;

    int srow = t >> 2;
    int scb  = (t & 3) * 8;

    uint4 ra0, ra1, rb0, rb1;
    {
        ra0 = *reinterpret_cast<const uint4*>(A + (size_t)(i0 + srow) * KDIM + scb);
        ra1 = *reinterpret_cast<const uint4*>(A + (size_t)(i0 + 64 + srow) * KDIM + scb);
        rb0 = *reinterpret_cast<const uint4*>(B + (size_t)(j0 + srow) * KDIM + scb);
        rb1 = *reinterpret_cast<const uint4*>(B + (size_t)(j0 + 64 + srow) * KDIM + scb);
    }

    for (int k0 = 0; k0 < KDIM; k0 += BK) {
        __syncthreads();
        *reinterpret_cast<uint4*>(As + (size_t)t * 8)         = ra0;
        *reinterpret_cast<uint4*>(As + (size_t)(256 + t) * 8) = ra1;
        *reinterpret_cast<uint4*>(Bs + (size_t)t * 8)         = rb0;
        *reinterpret_cast<uint4*>(Bs + (size_t)(256 + t) * 8) = rb1;
        __syncthreads();

        if (k0 + BK < KDIM) {
            int kn = k0 + BK;
            ra0 = *reinterpret_cast<const uint4*>(A + (size_t)(i0 + srow) * KDIM + kn + scb);
            ra1 = *reinterpret_cast<const uint4*>(A + (size_t)(i0 + 64 + srow) * KDIM + kn + scb);
            rb0 = *reinterpret_cast<const uint4*>(B + (size_t)(j0 + srow) * KDIM + kn + scb);
            rb1 = *reinterpret_cast<const uint4*>(B + (size_t)(j0 + 64 + srow) * KDIM + kn + scb);
        }

        bf16x8 af[4], bfr[4];
        #pragma unroll
        for (int m = 0; m < 4; ++m)
            af[m] = *reinterpret_cast<const bf16x8*>(As + (wr + m * 16 + frow) * BK + fk);
        #pragma unroll
        for (int n = 0; n < 4; ++n)
            bfr[n] = *reinterpret_cast<const bf16x8*>(Bs + (wc + n * 16 + frow) * BK + fk);

        #pragma unroll
        for (int m = 0; m < 4; ++m)
            #pragma unroll
            for (int n = 0; n < 4; ++n)
                acc[m][n] = __builtin_amdgcn_mfma_f32_16x16x32_bf16(af[m], bfr[n], acc[m][n], 0, 0, 0);
    }

    int crow = (lane >> 4) * 4;
    int ccol = lane & 15;
    #pragma unroll
    for (int n = 0; n < 4; ++n) {
        const int j  = j0 + wc + n * 16 + ccol;
        const int Lj = (j >> 2) & 63;
        #pragma unroll
        for (int m = 0; m < 4; ++m) {
            const int ibase = i0 + wr + m * 16 + crow;
            #pragma unroll
            for (int q = 0; q < 4; ++q)
                Cs[(size_t)(ibase + q + Lj) * NCOL + j] = f2bf(1.0f - acc[m][n][q]);
        }
    }
}

// ---------------------------------------------------------------------------
// ring_init: prefill dummy segment (index 15): tag = row+1, value = +INF.
// ---------------------------------------------------------------------------
__global__ __launch_bounds__(256) void ring_init(unsigned long long* __restrict__ ring)
{
    int i = blockIdx.x * 256 + threadIdx.x;
    ring[(size_t)15 * NROW + i] =
        ((unsigned long long)INFBITS << 32) | (unsigned)(i + 1);
}

// ---------------------------------------------------------------------------
// Kernel 3: systolic DTW, 16 WGs x 1 wave, free-running, 32-row blocks.
// CONSOLIDATION: R14's empirically-fastest body (simple min3 chain; DPP
// wave_shr with the boundary value injected through the DPP *old* operand
// -- one op, no cndmask) + R16's unclamped-slot fix (tail-block DMA race).
// R17 (closed form) and R18 (tree-min + bvec rotation) both measured
// slower; this reverts to the best-known configuration.
// ---------------------------------------------------------------------------
__global__ __launch_bounds__(64, 1) void dtw_systolic(
    const unsigned short* __restrict__ cost,   // skewed [SKROWS][4096]
    unsigned long long* __restrict__ ring,     // [16][4096] + garb[16][64]
    float* __restrict__ out)
{
    __shared__ __align__(16) unsigned char clds[2 * 16384];  // cost double-buffer
    __shared__ float outT[32];     // lane63's row-values for this block
    __shared__ float outD[64];     // per-lane dump (conflict-free)

    const int w    = blockIdx.x;
    const int lane = threadIdx.x;
    const char* skewb = (const char*)cost;
    const unsigned long long* rseg = ring + (size_t)((w == 0) ? 15 : (w - 1)) * NROW;
    unsigned long long* wseg = ring + (size_t)w * NROW;
    unsigned long long* garb = ring + (size_t)NWG * NROW + w * 64;
    const unsigned l32 = (unsigned)(lane & 31);
    const unsigned stripeByte = (unsigned)w * 512u + ((unsigned)(lane & 31) << 4);

    float pd0 = INFV, pd1 = INFV, pd2 = INFV, pd3 = INFV;
    float lprev = (w == 0 && lane == 0) ? 0.0f : INFV;   // DP origin seed
    float d3p = INFV;
    unsigned ansb = INFBITS;
    unsigned long long rv0 = 0, rv1 = 0, rv2 = 0;

// stage 32 rows of block STG into slot SLOT; rows clamped, slot from
// UNCLAMPED id at the call site (R8/R14 race fix)
#define GLL16S(STG, SLOT) { const int stg_ = (STG); \
    unsigned char* ldsb_ = clds + (SLOT) * 16384; \
    _Pragma("unroll") \
    for (int g_ = 0; g_ < 16; ++g_) { \
        int sr_ = 32 * stg_ + 2 * g_ + (lane >> 5); \
        if (sr_ > SKROWS - 1) sr_ = SKROWS - 1; \
        gll16(skewb + (size_t)sr_ * 8192 + stripeByte, ldsb_ + g_ * 1024); } }

// asm tag/value preload: invisible to compiler waitcnt pass, L2-bypass
#define RINGLD(DST, BI) { int pb_ = (BI); pb_ = pb_ < 0 ? 0 : (pb_ > 127 ? 127 : pb_); \
    const unsigned off_ = (32u * (unsigned)pb_ + l32) * 8u; \
    asm volatile("global_load_dwordx2 %0, %1, %2 sc0 sc1" \
                 : "=v"(DST) : "v"(off_), "s"(rseg) : "memory"); }

// R14 body: min3 chain; DPP old-operand injects boundary for lane 0
#define DCOMP(K, CU) { \
    const unsigned rbK = (unsigned)__builtin_amdgcn_readlane(rvhi, (K)); \
    const float lcur = __uint_as_float((unsigned)__builtin_amdgcn_update_dpp( \
        (int)rbK, (int)__float_as_uint(d3p), 0x138, 0xf, 0xf, false)); \
    const float c0 = __uint_as_float(CU.x << 16); \
    const float c1 = __uint_as_float(CU.x & 0xffff0000u); \
    const float c2 = __uint_as_float(CU.y << 16); \
    const float c3 = __uint_as_float(CU.y & 0xffff0000u); \
    const float n0 = c0 + fminf(pd0, lprev); \
    const float n1 = c1 + fminf(pd1, pd0); \
    const float n2 = c2 + fminf(pd2, pd1); \
    const float n3 = c3 + fminf(pd3, pd2); \
    const float e0 = fminf(lcur + c0, n0); \
    const float e1 = fminf(e0 + c1, n1); \
    const float e2 = fminf(e1 + c2, n2); \
    const float e3 = fminf(e2 + c3, n3); \
    float* sp_ = (lane == 63) ? &outT[K] : &outD[lane]; \
    *sp_ = e3; \
    ansb = (tjb + (K) == 4158) ? __float_as_uint(e3) : ansb; \
    lprev = lcur; d3p = e3; \
    pd0 = e0; pd1 = e1; pd2 = e2; pd3 = e3; }

    // prologue: stage block 0 -> slot 0, preload tags for blocks 0..2
    GLL16S(0, 0)
    RINGLD(rv0, 0) RINGLD(rv1, 1) RINGLD(rv2, 2)
    CFENCE;

    #pragma unroll 1
    for (int ib = 0; ib < NBLK32; ++ib) {
        GLL16S(ib + 1, (ib + 1) & 1)       // slot from UNCLAMPED id
        unsigned long long rvN;
        RINGLD(rvN, ib + 3)
        CFENCE;
        // forces prev block's 16 glls (read slot) + transitively rv0
        asm volatile("s_waitcnt vmcnt(19)" : "+v"(rv0) :: "memory");

        // tag check for this block (rows 32ib..32ib+31)
        if (ib < 128) {
            const unsigned expt = 32u * (unsigned)ib + l32 + 1u;
            while (__ballot((unsigned)rv0 == expt) != ~0ull)
                rv0 = __hip_atomic_load(rseg + 32u * (unsigned)ib + l32,
                                        __ATOMIC_RELAXED, __HIP_MEMORY_SCOPE_AGENT);
        }
        const int rvhi = (int)(unsigned)(rv0 >> 32);

        // batch-load the 32 cost uint2s into named regs
        const uint2* lu = reinterpret_cast<const uint2*>(
            clds + (ib & 1) * 16384 + (lane << 3));
        const uint2 cc0  = lu[0 * 64],  cc1  = lu[1 * 64];
        const uint2 cc2  = lu[2 * 64],  cc3  = lu[3 * 64];
        const uint2 cc4  = lu[4 * 64],  cc5  = lu[5 * 64];
        const uint2 cc6  = lu[6 * 64],  cc7  = lu[7 * 64];
        const uint2 cc8  = lu[8 * 64],  cc9  = lu[9 * 64];
        const uint2 cc10 = lu[10 * 64], cc11 = lu[11 * 64];
        const uint2 cc12 = lu[12 * 64], cc13 = lu[13 * 64];
        const uint2 cc14 = lu[14 * 64], cc15 = lu[15 * 64];
        const uint2 cc16 = lu[16 * 64], cc17 = lu[17 * 64];
        const uint2 cc18 = lu[18 * 64], cc19 = lu[19 * 64];
        const uint2 cc20 = lu[20 * 64], cc21 = lu[21 * 64];
        const uint2 cc22 = lu[22 * 64], cc23 = lu[23 * 64];
        const uint2 cc24 = lu[24 * 64], cc25 = lu[25 * 64];
        const uint2 cc26 = lu[26 * 64], cc27 = lu[27 * 64];
        const uint2 cc28 = lu[28 * 64], cc29 = lu[29 * 64];
        const uint2 cc30 = lu[30 * 64], cc31 = lu[31 * 64];

        const int rowbase = 32 * ib - 63;
        const int tjb = 32 * ib;

        DCOMP(0,  cc0)  DCOMP(1,  cc1)  DCOMP(2,  cc2)  DCOMP(3,  cc3)
        DCOMP(4,  cc4)  DCOMP(5,  cc5)  DCOMP(6,  cc6)  DCOMP(7,  cc7)
        DCOMP(8,  cc8)  DCOMP(9,  cc9)  DCOMP(10, cc10) DCOMP(11, cc11)
        DCOMP(12, cc12) DCOMP(13, cc13) DCOMP(14, cc14) DCOMP(15, cc15)
        DCOMP(16, cc16) DCOMP(17, cc17) DCOMP(18, cc18) DCOMP(19, cc19)
        DCOMP(20, cc20) DCOMP(21, cc21) DCOMP(22, cc22) DCOMP(23, cc23)
        DCOMP(24, cc24) DCOMP(25, cc25) DCOMP(26, cc26) DCOMP(27, cc27)
        DCOMP(28, cc28) DCOMP(29, cc29) DCOMP(30, cc30) DCOMP(31, cc31)

        // publish 32 boundary rows (lane k -> row rowbase+k), garb if invalid
        {
            const float bv = outT[l32];
            const int r = rowbase + (int)l32;
            const bool valid = (lane < 32) && (r >= 0) && (r <= 4095) &&
                               (w < NWG - 1);
            if (lane < 32) {
                const unsigned long long pk =
                    ((unsigned long long)__float_as_uint(bv) << 32) | (unsigned)(r + 1);
                unsigned long long* sp = valid ? (wseg + r) : (garb + lane);
                (void)__hip_atomic_exchange(sp, pk, __ATOMIC_RELAXED,
                                            __HIP_MEMORY_SCOPE_AGENT);
            }
        }
        CFENCE;

        rv0 = rv1; rv1 = rv2; rv2 = rvN;
    }

#undef GLL16S
#undef RINGLD
#undef DCOMP

    if (w == NWG - 1 && lane == 63)
        out[0] = 1.0f / (1.0f + __uint_as_float(ansb));
}

// ---------------------------------------------------------------------------
extern "C" void kernel_launch(void* const* d_in, const int* in_sizes, int n_in,
                              void* d_out, int out_size, void* d_ws, size_t ws_size,
                              hipStream_t stream)
{
    const float* t1 = (const float*)d_in[0];
    const float* t2 = (const float*)d_in[1];
    float* out = (float*)d_out;

    char* ws = (char*)d_ws;
    unsigned short* t1n  = (unsigned short*)ws;                                   // 8 MB
    unsigned short* t2n  = (unsigned short*)(ws + (size_t)NROW * KDIM * 2);       // 8 MB
    unsigned short* skew = (unsigned short*)(ws + (size_t)16 * 1024 * 1024);      // 34.1 MB
    unsigned long long* ring = (unsigned long long*)(ws + (size_t)52 * 1024 * 1024);
    // ring: segs 0..14 real interfaces, seg 15 = dummy-INF, 16x64 garb

    hipMemsetAsync(ring, 0, (size_t)15 * NROW * 8, stream);
    ring_init<<<NROW / 256, 256, 0, stream>>>(ring);
    normalize_bf16<<<2 * NROW, 256, 0, stream>>>(t1, t2, t1n, t2n);
    gemm_cost<<<dim3(NCOL / BM, NROW / BM), 256, 0, stream>>>(t1n, t2n, skew);
    dtw_systolic<<<NWG, 64, 0, stream>>>(skew, ring, out);
}

// Round 21
// 516.608 us; speedup vs baseline: 4.0399x; 1.0026x over previous
//
#include <hip/hip_runtime.h>
#include <hip/hip_bf16.h>
#include <stdint.h>

#define KDIM 1024
#define NROW 4096
#define NCOL 4096
#define INFV 1e30f
#define INFBITS 0x7149F2CAu     // bits of 1e30f
#define BM 128
#define BK 32

#define SKROWS 4160             // skewed cost rows
#define NBLK32 130              // 32-step blocks (tj 0..4159)
#define NWG    16

typedef __bf16 bf16x8 __attribute__((ext_vector_type(8)));
typedef float f32x4 __attribute__((ext_vector_type(4)));

#define CFENCE asm volatile("" ::: "memory")

__device__ __forceinline__ unsigned short f2bf(float f) {
    __hip_bfloat16 h = __float2bfloat16(f);
    return *reinterpret_cast<unsigned short*>(&h);
}

__device__ __forceinline__ void gll16(const void* gsrc, void* ldst) {
    __builtin_amdgcn_global_load_lds(
        (const __attribute__((address_space(1))) void*)gsrc,
        (__attribute__((address_space(3))) void*)ldst, 16, 0, 0);
}

// ---------------------------------------------------------------------------
// Kernel 1: row-normalize both trajectories, emit bf16
// ---------------------------------------------------------------------------
__global__ __launch_bounds__(256) void normalize_bf16(
    const float* __restrict__ t1, const float* __restrict__ t2,
    unsigned short* __restrict__ o1, unsigned short* __restrict__ o2)
{
    int b = blockIdx.x;
    int t = threadIdx.x;
    const float* src;
    unsigned short* dst;
    if (b < NROW) { src = t1 + (size_t)b * KDIM;          dst = o1 + (size_t)b * KDIM; }
    else          { src = t2 + (size_t)(b - NROW) * KDIM; dst = o2 + (size_t)(b - NROW) * KDIM; }

    float4 v = reinterpret_cast<const float4*>(src)[t];
    float ss = v.x * v.x + v.y * v.y + v.z * v.z + v.w * v.w;
    #pragma unroll
    for (int d = 32; d >= 1; d >>= 1) ss += __shfl_xor(ss, d, 64);

    __shared__ float wsum[4];
    int wave = t >> 6;
    if ((t & 63) == 0) wsum[wave] = ss;
    __syncthreads();
    float inv = 1.0f / (sqrtf(wsum[0] + wsum[1] + wsum[2] + wsum[3]) + 1e-8f);

    ushort4 o;
    o.x = f2bf(v.x * inv);
    o.y = f2bf(v.y * inv);
    o.z = f2bf(v.z * inv);
    o.w = f2bf(v.w * inv);
    reinterpret_cast<ushort4*>(dst)[t] = o;
}

// ---------------------------------------------------------------------------
// Kernel 2: skewed cost: skew[i + ((j>>2)&63)][j] = 1 - dot(t1n[i], t2n[j])
// ---------------------------------------------------------------------------
__global__ __launch_bounds__(256) void gemm_cost(
    const unsigned short* __restrict__ A,
    const unsigned short* __restrict__ B,
    unsigned short* __restrict__ Cs)    // skewed [SKROWS][4096]
{
    __shared__ __align__(16) unsigned short As[BM * BK];
    __shared__ __align__(16) unsigned short Bs[BM * BK];

    int t    = threadIdx.x;
    int lane = t & 63;
    int wave = t >> 6;
    int i0   = blockIdx.y * BM;
    int j0   = blockIdx.x * BM;

    f32x4 acc[4][4];
    f32x4 zero = {0.f, 0.f, 0.f, 0.f};
    #pragma unroll
    for (int m = 0; m < 4; ++m)
        #pragma unroll
        for (int n = 0; n < 4; ++n) acc[m][n] = zero;

    int frow = lane & 15;
    int fk   = (lane >> 4) * 8;
    int wr   = (wave >> 1) * 64;
    int wc   = (wave & 1) * 64;

    int srow = t >> 2;
    int scb  = (t & 3) * 8;

    uint4 ra0, ra1, rb0, rb1;
    {
        ra0 = *reinterpret_cast<const uint4*>(A + (size_t)(i0 + srow) * KDIM + scb);
        ra1 = *reinterpret_cast<const uint4*>(A + (size_t)(i0 + 64 + srow) * KDIM + scb);
        rb0 = *reinterpret_cast<const uint4*>(B + (size_t)(j0 + srow) * KDIM + scb);
        rb1 = *reinterpret_cast<const uint4*>(B + (size_t)(j0 + 64 + srow) * KDIM + scb);
    }

    for (int k0 = 0; k0 < KDIM; k0 += BK) {
        __syncthreads();
        *reinterpret_cast<uint4*>(As + (size_t)t * 8)         = ra0;
        *reinterpret_cast<uint4*>(As + (size_t)(256 + t) * 8) = ra1;
        *reinterpret_cast<uint4*>(Bs + (size_t)t * 8)         = rb0;
        *reinterpret_cast<uint4*>(Bs + (size_t)(256 + t) * 8) = rb1;
        __syncthreads();

        if (k0 + BK < KDIM) {
            int kn = k0 + BK;
            ra0 = *reinterpret_cast<const uint4*>(A + (size_t)(i0 + srow) * KDIM + kn + scb);
            ra1 = *reinterpret_cast<const uint4*>(A + (size_t)(i0 + 64 + srow) * KDIM + kn + scb);
            rb0 = *reinterpret_cast<const uint4*>(B + (size_t)(j0 + srow) * KDIM + kn + scb);
            rb1 = *reinterpret_cast<const uint4*>(B + (size_t)(j0 + 64 + srow) * KDIM + kn + scb);
        }

        bf16x8 af[4], bfr[4];
        #pragma unroll
        for (int m = 0; m < 4; ++m)
            af[m] = *reinterpret_cast<const bf16x8*>(As + (wr + m * 16 + frow) * BK + fk);
        #pragma unroll
        for (int n = 0; n < 4; ++n)
            bfr[n] = *reinterpret_cast<const bf16x8*>(Bs + (wc + n * 16 + frow) * BK + fk);

        #pragma unroll
        for (int m = 0; m < 4; ++m)
            #pragma unroll
            for (int n = 0; n < 4; ++n)
                acc[m][n] = __builtin_amdgcn_mfma_f32_16x16x32_bf16(af[m], bfr[n], acc[m][n], 0, 0, 0);
    }

    int crow = (lane >> 4) * 4;
    int ccol = lane & 15;
    #pragma unroll
    for (int n = 0; n < 4; ++n) {
        const int j  = j0 + wc + n * 16 + ccol;
        const int Lj = (j >> 2) & 63;
        #pragma unroll
        for (int m = 0; m < 4; ++m) {
            const int ibase = i0 + wr + m * 16 + crow;
            #pragma unroll
            for (int q = 0; q < 4; ++q)
                Cs[(size_t)(ibase + q + Lj) * NCOL + j] = f2bf(1.0f - acc[m][n][q]);
        }
    }
}

// ---------------------------------------------------------------------------
// ring_init: prefill dummy segment (index 15): tag = row+1, value = +INF.
// ---------------------------------------------------------------------------
__global__ __launch_bounds__(256) void ring_init(unsigned long long* __restrict__ ring)
{
    int i = blockIdx.x * 256 + threadIdx.x;
    ring[(size_t)15 * NROW + i] =
        ((unsigned long long)INFBITS << 32) | (unsigned)(i + 1);
}

// ---------------------------------------------------------------------------
// Kernel 3: systolic DTW, 16 WGs x 1 wave, free-running, 32-row blocks.
// vs R19 (two changes, rest identical):
//  (1) DEEP PREFETCH: 8-slot LDS ring, gll prefetch 3 blocks ahead, one
//      s_waitcnt vmcnt(55)/block. vmcnt is an ORDERED queue: forcing block
//      ib-1's glls (R19's vmcnt(19)) transitively forced block ib-2's
//      publish op -> steady state c = publish-ack/2 = 3.34us. Forcing
//      ib-3's glls instead pushes the forced publish to ib-4 (gap 2->4
//      block-times).
//  (2) publish = atomic_store (write-through, no RMW return trip) instead
//      of atomic_exchange.
// ---------------------------------------------------------------------------
__global__ __launch_bounds__(64, 1) void dtw_systolic(
    const unsigned short* __restrict__ cost,   // skewed [SKROWS][4096]
    unsigned long long* __restrict__ ring,     // [16][4096] + garb[16][64]
    float* __restrict__ out)
{
    __shared__ __align__(16) unsigned char clds[8 * 16384];  // 8-slot cost ring
    __shared__ float outT[32];     // lane63's row-values for this block
    __shared__ float outD[64];     // per-lane dump (conflict-free)

    const int w    = blockIdx.x;
    const int lane = threadIdx.x;
    const char* skewb = (const char*)cost;
    const unsigned long long* rseg = ring + (size_t)((w == 0) ? 15 : (w - 1)) * NROW;
    unsigned long long* wseg = ring + (size_t)w * NROW;
    unsigned long long* garb = ring + (size_t)NWG * NROW + w * 64;
    const unsigned l32 = (unsigned)(lane & 31);
    const unsigned stripeByte = (unsigned)w * 512u + ((unsigned)(lane & 31) << 4);

    float pd0 = INFV, pd1 = INFV, pd2 = INFV, pd3 = INFV;
    float lprev = (w == 0 && lane == 0) ? 0.0f : INFV;   // DP origin seed
    float d3p = INFV;
    unsigned ansb = INFBITS;
    unsigned long long rv0 = 0, rv1 = 0, rv2 = 0;

// stage 32 rows of block STG into slot SLOT; rows clamped, slot from
// UNCLAMPED id at the call site (disjoint from read slot mod 8)
#define GLL16S(STG, SLOT) { int stg_ = (STG); \
    stg_ = stg_ > NBLK32 - 1 ? NBLK32 - 1 : stg_; \
    unsigned char* ldsb_ = clds + (SLOT) * 16384; \
    _Pragma("unroll") \
    for (int g_ = 0; g_ < 16; ++g_) { \
        int sr_ = 32 * stg_ + 2 * g_ + (lane >> 5); \
        if (sr_ > SKROWS - 1) sr_ = SKROWS - 1; \
        gll16(skewb + (size_t)sr_ * 8192 + stripeByte, ldsb_ + g_ * 1024); } }

// asm tag/value preload: invisible to compiler waitcnt pass, L2-bypass
#define RINGLD(DST, BI) { int pb_ = (BI); pb_ = pb_ < 0 ? 0 : (pb_ > 127 ? 127 : pb_); \
    const unsigned off_ = (32u * (unsigned)pb_ + l32) * 8u; \
    asm volatile("global_load_dwordx2 %0, %1, %2 sc0 sc1" \
                 : "=v"(DST) : "v"(off_), "s"(rseg) : "memory"); }

// R14 body: min3 chain; DPP old-operand injects boundary for lane 0
#define DCOMP(K, CU) { \
    const unsigned rbK = (unsigned)__builtin_amdgcn_readlane(rvhi, (K)); \
    const float lcur = __uint_as_float((unsigned)__builtin_amdgcn_update_dpp( \
        (int)rbK, (int)__float_as_uint(d3p), 0x138, 0xf, 0xf, false)); \
    const float c0 = __uint_as_float(CU.x << 16); \
    const float c1 = __uint_as_float(CU.x & 0xffff0000u); \
    const float c2 = __uint_as_float(CU.y << 16); \
    const float c3 = __uint_as_float(CU.y & 0xffff0000u); \
    const float n0 = c0 + fminf(pd0, lprev); \
    const float n1 = c1 + fminf(pd1, pd0); \
    const float n2 = c2 + fminf(pd2, pd1); \
    const float n3 = c3 + fminf(pd3, pd2); \
    const float e0 = fminf(lcur + c0, n0); \
    const float e1 = fminf(e0 + c1, n1); \
    const float e2 = fminf(e1 + c2, n2); \
    const float e3 = fminf(e2 + c3, n3); \
    float* sp_ = (lane == 63) ? &outT[K] : &outD[lane]; \
    *sp_ = e3; \
    ansb = (tjb + (K) == 4158) ? __float_as_uint(e3) : ansb; \
    lprev = lcur; d3p = e3; \
    pd0 = e0; pd1 = e1; pd2 = e2; pd3 = e3; }

    // prologue: stage blocks 0..2 -> slots 0..2, preload tags 0..2, then
    // drain the prologue glls (one-time) so early-block waits can't
    // under-force the slots they read.
    GLL16S(0, 0) GLL16S(1, 1) GLL16S(2, 2)
    RINGLD(rv0, 0) RINGLD(rv1, 1) RINGLD(rv2, 2)
    asm volatile("s_waitcnt vmcnt(3)" ::: "memory");   // all 48 glls done
    CFENCE;

    #pragma unroll 1
    for (int ib = 0; ib < NBLK32; ++ib) {
        GLL16S(ib + 3, (ib + 3) & 7)       // prefetch 3 ahead (slot unclamped)
        unsigned long long rvN;
        RINGLD(rvN, ib + 3)
        CFENCE;
        // 18 ops/block (16 gll + 1 ringld + 1 publish). Allowed newest =
        // ib's 17 + (ib-1,ib-2)'s 36 + ib-3's ringld+publish = 55 ->
        // forces ib-3's glls (this block's read slot) + ib-4's publish.
        asm volatile("s_waitcnt vmcnt(55)" : "+v"(rv0) :: "memory");

        // tag check for this block (rows 32ib..32ib+31)
        if (ib < 128) {
            const unsigned expt = 32u * (unsigned)ib + l32 + 1u;
            while (__ballot((unsigned)rv0 == expt) != ~0ull)
                rv0 = __hip_atomic_load(rseg + 32u * (unsigned)ib + l32,
                                        __ATOMIC_RELAXED, __HIP_MEMORY_SCOPE_AGENT);
        }
        const int rvhi = (int)(unsigned)(rv0 >> 32);

        // batch-load the 32 cost uint2s into named regs
        const uint2* lu = reinterpret_cast<const uint2*>(
            clds + (ib & 7) * 16384 + (lane << 3));
        const uint2 cc0  = lu[0 * 64],  cc1  = lu[1 * 64];
        const uint2 cc2  = lu[2 * 64],  cc3  = lu[3 * 64];
        const uint2 cc4  = lu[4 * 64],  cc5  = lu[5 * 64];
        const uint2 cc6  = lu[6 * 64],  cc7  = lu[7 * 64];
        const uint2 cc8  = lu[8 * 64],  cc9  = lu[9 * 64];
        const uint2 cc10 = lu[10 * 64], cc11 = lu[11 * 64];
        const uint2 cc12 = lu[12 * 64], cc13 = lu[13 * 64];
        const uint2 cc14 = lu[14 * 64], cc15 = lu[15 * 64];
        const uint2 cc16 = lu[16 * 64], cc17 = lu[17 * 64];
        const uint2 cc18 = lu[18 * 64], cc19 = lu[19 * 64];
        const uint2 cc20 = lu[20 * 64], cc21 = lu[21 * 64];
        const uint2 cc22 = lu[22 * 64], cc23 = lu[23 * 64];
        const uint2 cc24 = lu[24 * 64], cc25 = lu[25 * 64];
        const uint2 cc26 = lu[26 * 64], cc27 = lu[27 * 64];
        const uint2 cc28 = lu[28 * 64], cc29 = lu[29 * 64];
        const uint2 cc30 = lu[30 * 64], cc31 = lu[31 * 64];

        const int rowbase = 32 * ib - 63;
        const int tjb = 32 * ib;

        DCOMP(0,  cc0)  DCOMP(1,  cc1)  DCOMP(2,  cc2)  DCOMP(3,  cc3)
        DCOMP(4,  cc4)  DCOMP(5,  cc5)  DCOMP(6,  cc6)  DCOMP(7,  cc7)
        DCOMP(8,  cc8)  DCOMP(9,  cc9)  DCOMP(10, cc10) DCOMP(11, cc11)
        DCOMP(12, cc12) DCOMP(13, cc13) DCOMP(14, cc14) DCOMP(15, cc15)
        DCOMP(16, cc16) DCOMP(17, cc17) DCOMP(18, cc18) DCOMP(19, cc19)
        DCOMP(20, cc20) DCOMP(21, cc21) DCOMP(22, cc22) DCOMP(23, cc23)
        DCOMP(24, cc24) DCOMP(25, cc25) DCOMP(26, cc26) DCOMP(27, cc27)
        DCOMP(28, cc28) DCOMP(29, cc29) DCOMP(30, cc30) DCOMP(31, cc31)

        // publish 32 boundary rows via write-through atomic STORE (no RMW)
        {
            const float bv = outT[l32];
            const int r = rowbase + (int)l32;
            const bool valid = (lane < 32) && (r >= 0) && (r <= 4095) &&
                               (w < NWG - 1);
            if (lane < 32) {
                const unsigned long long pk =
                    ((unsigned long long)__float_as_uint(bv) << 32) | (unsigned)(r + 1);
                unsigned long long* sp = valid ? (wseg + r) : (garb + lane);
                __hip_atomic_store(sp, pk, __ATOMIC_RELAXED,
                                   __HIP_MEMORY_SCOPE_AGENT);
            }
        }
        CFENCE;

        rv0 = rv1; rv1 = rv2; rv2 = rvN;
    }

#undef GLL16S
#undef RINGLD
#undef DCOMP

    if (w == NWG - 1 && lane == 63)
        out[0] = 1.0f / (1.0f + __uint_as_float(ansb));
}

// ---------------------------------------------------------------------------
extern "C" void kernel_launch(void* const* d_in, const int* in_sizes, int n_in,
                              void* d_out, int out_size, void* d_ws, size_t ws_size,
                              hipStream_t stream)
{
    const float* t1 = (const float*)d_in[0];
    const float* t2 = (const float*)d_in[1];
    float* out = (float*)d_out;

    char* ws = (char*)d_ws;
    unsigned short* t1n  = (unsigned short*)ws;                                   // 8 MB
    unsigned short* t2n  = (unsigned short*)(ws + (size_t)NROW * KDIM * 2);       // 8 MB
    unsigned short* skew = (unsigned short*)(ws + (size_t)16 * 1024 * 1024);      // 34.1 MB
    unsigned long long* ring = (unsigned long long*)(ws + (size_t)52 * 1024 * 1024);
    // ring: segs 0..14 real interfaces, seg 15 = dummy-INF, 16x64 garb

    hipMemsetAsync(ring, 0, (size_t)15 * NROW * 8, stream);
    ring_init<<<NROW / 256, 256, 0, stream>>>(ring);
    normalize_bf16<<<2 * NROW, 256, 0, stream>>>(t1, t2, t1n, t2n);
    gemm_cost<<<dim3(NCOL / BM, NROW / BM), 256, 0, stream>>>(t1n, t2n, skew);
    dtw_systolic<<<NWG, 64, 0, stream>>>(skew, ring, out);
}